// Round 1
// baseline (267.234 us; speedup 1.0000x reference)
//
#include <hip/hip_runtime.h>
#include <hip/hip_bf16.h>

typedef __bf16 bf16;
typedef __bf16 bf16x4 __attribute__((ext_vector_type(4)));
typedef __bf16 bf16x8 __attribute__((ext_vector_type(8)));
typedef float f32x4 __attribute__((ext_vector_type(4)));

#define NB 8
#define NS 2048
#define ND 512

static __device__ __forceinline__ f32x4 mfma16(bf16x8 a, bf16x8 b, f32x4 c) {
  return __builtin_amdgcn_mfma_f32_16x16x32_bf16(a, b, c, 0, 0, 0);
}

// ---- kernel 0: W[k][n] (f32) -> Wt[n][k] (bf16), 3 weights concatenated ----
__global__ void wconv_kernel(const float* __restrict__ Wq,
                             const float* __restrict__ Wk,
                             const float* __restrict__ Wv,
                             bf16* __restrict__ Wt) {
  int idx = blockIdx.x * 256 + threadIdx.x;        // 3 * 512 * 512
  int w = idx >> 18;
  int rem = idx & ((1 << 18) - 1);
  int n = rem >> 9, k = rem & 511;
  const float* W = (w == 0) ? Wq : (w == 1) ? Wk : Wv;
  Wt[idx] = (bf16)W[k * 512 + n];
}

// ---- kernel 1: C[16384,512] = A_f32[16384,512] @ W, bf16 out ----
// vmode=0: row-major C; vmode=1: per-batch transposed C (V^T: [B][512][2048])
__launch_bounds__(256)
__global__ void proj_kernel(const float* __restrict__ A,
                            const bf16* __restrict__ Wt,   // [512 n][512 k]
                            bf16* __restrict__ C,
                            int vmode) {
  __shared__ bf16 As[2][128][72];
  __shared__ bf16 Ws[2][128][72];
  const int t = threadIdx.x;
  const int lane = t & 63;
  const int w = t >> 6;
  const int wr = w >> 1, wc = w & 1;                // 2x2 waves, 64x64 each
  const int bm = blockIdx.x * 128;
  const int bn = blockIdx.y * 128;

  f32x4 acc[4][4] = {};

  auto stageA = [&](int kc, int bufi) {
    int r0 = t >> 4, seg = t & 15;                  // 16 lanes * 16B = 256B contig
#pragma unroll
    for (int p = 0; p < 8; ++p) {
      int r = p * 16 + r0;
      float4 v = *(const float4*)(A + (size_t)(bm + r) * 512 + kc * 64 + seg * 4);
      bf16x4 o = {(bf16)v.x, (bf16)v.y, (bf16)v.z, (bf16)v.w};
      *(bf16x4*)&As[bufi][r][seg * 4] = o;
    }
  };
  auto stageW = [&](int kc, int bufi) {
    int n0 = t >> 3, seg = t & 7;                   // 8 lanes * 16B = 128B contig
#pragma unroll
    for (int p = 0; p < 4; ++p) {
      int n = p * 32 + n0;
      bf16x8 v = *(const bf16x8*)(Wt + (size_t)(bn + n) * 512 + kc * 64 + seg * 8);
      *(bf16x8*)&Ws[bufi][n][seg * 8] = v;
    }
  };

  stageA(0, 0);
  stageW(0, 0);
  __syncthreads();
  int buf = 0;
  for (int kc = 0; kc < 8; ++kc) {
    if (kc < 7) { stageA(kc + 1, buf ^ 1); stageW(kc + 1, buf ^ 1); }
    const int arow = lane & 15, kq = (lane >> 4) * 8;
#pragma unroll
    for (int kk = 0; kk < 2; ++kk) {
      bf16x8 af[4], bfr[4];
#pragma unroll
      for (int mi = 0; mi < 4; ++mi)
        af[mi] = *(const bf16x8*)&As[buf][wr * 64 + mi * 16 + arow][kk * 32 + kq];
#pragma unroll
      for (int ni = 0; ni < 4; ++ni)
        bfr[ni] = *(const bf16x8*)&Ws[buf][wc * 64 + ni * 16 + arow][kk * 32 + kq];
#pragma unroll
      for (int mi = 0; mi < 4; ++mi)
#pragma unroll
        for (int ni = 0; ni < 4; ++ni)
          acc[mi][ni] = mfma16(af[mi], bfr[ni], acc[mi][ni]);
    }
    __syncthreads();
    buf ^= 1;
  }

  // epilogue: C/D layout col=lane&15, row=(lane>>4)*4+j  [m89]
  const int row0 = (lane >> 4) * 4, col = lane & 15;
#pragma unroll
  for (int mi = 0; mi < 4; ++mi)
#pragma unroll
    for (int ni = 0; ni < 4; ++ni) {
      int cg = bn + wc * 64 + ni * 16 + col;
#pragma unroll
      for (int j = 0; j < 4; ++j) {
        int rg = bm + wr * 64 + mi * 16 + row0 + j;
        bf16 o = (bf16)acc[mi][ni][j];
        if (vmode) {
          int bb = rg >> 11, s = rg & 2047;
          C[(size_t)bb * (ND * NS) + (size_t)cg * NS + s] = o;
        } else {
          C[(size_t)rg * ND + cg] = o;
        }
      }
    }
}

// ---- kernel 2: causal flash attention ----
// grid (32 pairs, 8 batches), 512 threads (8 waves).
// Block handles q-tiles p and 63-p (32 rows each) => constant 33 KV-tiles/block.
__launch_bounds__(512)
__global__ void attn_kernel(const bf16* __restrict__ Qg,   // [B][S][D]
                            const bf16* __restrict__ Kg,   // [B][S][D]
                            const bf16* __restrict__ Vtg,  // [B][D][S]
                            float* __restrict__ Out) {     // [B][S][D]
  __shared__ bf16 Qs[32][520];
  __shared__ bf16 Vts[512][72];
  __shared__ bf16 Ks[2][64][72];
  __shared__ float Ss[32][68];
  __shared__ bf16 Ps[32][72];
  __shared__ float m_lds[32], l_lds[32], r_lds[32];

  const int t = threadIdx.x;
  const int lane = t & 63;
  const int w = t >> 6;
  const int b = blockIdx.y;
  const int pidx = blockIdx.x;

  const bf16* Qb = Qg + (size_t)b * NS * ND;
  const bf16* Kb = Kg + (size_t)b * NS * ND;
  const bf16* Vb = Vtg + (size_t)b * ND * NS;
  float* Ob = Out + (size_t)b * NS * ND;

  // fold 1/sqrt(512) and log2(e): softmax done in exp2 domain
  const float SC = 0.04419417382415922f * 1.4426950408889634f;

  for (int half = 0; half < 2; ++half) {
    const int qt = half ? (63 - pidx) : pidx;
    const int q0 = qt * 32;
    __syncthreads();
    {  // stage Q tile [32][512]
      int r = t >> 4, seg = t & 15;
#pragma unroll
      for (int i = 0; i < 4; ++i) {
        bf16x8 v = *(const bf16x8*)(Qb + (size_t)(q0 + r) * 512 + i * 128 + seg * 8);
        *(bf16x8*)&Qs[r][i * 128 + seg * 8] = v;
      }
    }
    if (t < 32) { m_lds[t] = -1e30f; l_lds[t] = 0.0f; }
    f32x4 acc[2][4] = {};
    __syncthreads();

    const int n_tiles = (qt >> 1) + 1;
    for (int it = 0; it < n_tiles; ++it) {
      const int k0 = it * 64;
      {  // stage V^T tile [512 d][64 kv]
        int dr = t >> 3, seg = t & 7;
#pragma unroll
        for (int pp = 0; pp < 8; ++pp) {
          int d = pp * 64 + dr;
          bf16x8 v = *(const bf16x8*)(Vb + (size_t)d * NS + k0 + seg * 8);
          *(bf16x8*)&Vts[d][seg * 8] = v;
        }
      }
      {  // stage K chunk 0: [64 kv][64 d]
        int kr = t >> 3, seg = t & 7;
        bf16x8 v = *(const bf16x8*)(Kb + (size_t)(k0 + kr) * 512 + seg * 8);
        *(bf16x8*)&Ks[0][kr][seg * 8] = v;
      }
      __syncthreads();

      // ---- scores: S = Q(32x512) K^T, K streamed in 8 d-chunks, dbuf ----
      f32x4 sacc = {};
      const int sr = w >> 2, sc = w & 3;   // wave sub-tile 16x16 of 32x64
      int buf = 0;
      for (int kc = 0; kc < 8; ++kc) {
        if (kc < 7) {
          int kr = t >> 3, seg = t & 7;
          bf16x8 v = *(const bf16x8*)(Kb + (size_t)(k0 + kr) * 512 + (kc + 1) * 64 + seg * 8);
          *(bf16x8*)&Ks[buf ^ 1][kr][seg * 8] = v;
        }
        const int arow = lane & 15, kq = (lane >> 4) * 8;
#pragma unroll
        for (int kk = 0; kk < 2; ++kk) {
          bf16x8 a = *(const bf16x8*)&Qs[sr * 16 + arow][kc * 64 + kk * 32 + kq];
          bf16x8 bb = *(const bf16x8*)&Ks[buf][sc * 16 + arow][kk * 32 + kq];
          sacc = mfma16(a, bb, sacc);
        }
        __syncthreads();
        buf ^= 1;
      }
      {  // write scores with scale + causal mask
        const int col = lane & 15, row0 = (lane >> 4) * 4;
#pragma unroll
        for (int j = 0; j < 4; ++j) {
          int qr = sr * 16 + row0 + j;
          int kcol = sc * 16 + col;
          float v = sacc[j] * SC;
          if (k0 + kcol > q0 + qr) v = -1e30f;
          Ss[qr][kcol] = v;
        }
      }
      __syncthreads();
      {  // wave-parallel online softmax: 32 rows x 16 lanes
        const int row = t >> 4, sub = t & 15;
        float4 sv = *(const float4*)&Ss[row][sub * 4];
        float mx = fmaxf(fmaxf(sv.x, sv.y), fmaxf(sv.z, sv.w));
#pragma unroll
        for (int d = 1; d < 16; d <<= 1) mx = fmaxf(mx, __shfl_xor(mx, d));
        float m_old = m_lds[row];
        float m_new = fmaxf(m_old, mx);
        float p0 = exp2f(sv.x - m_new), p1 = exp2f(sv.y - m_new);
        float p2 = exp2f(sv.z - m_new), p3 = exp2f(sv.w - m_new);
        float sum = (p0 + p1) + (p2 + p3);
#pragma unroll
        for (int d = 1; d < 16; d <<= 1) sum += __shfl_xor(sum, d);
        bf16x4 pv = {(bf16)p0, (bf16)p1, (bf16)p2, (bf16)p3};
        *(bf16x4*)&Ps[row][sub * 4] = pv;
        if (sub == 0) {
          float rs = exp2f(m_old - m_new);
          r_lds[row] = rs;
          m_lds[row] = m_new;
          l_lds[row] = l_lds[row] * rs + sum;
        }
      }
      __syncthreads();
      {  // rescale acc + PV: each wave owns out cols [64w, 64w+64)
        const int row0 = (lane >> 4) * 4;
#pragma unroll
        for (int mi = 0; mi < 2; ++mi)
#pragma unroll
          for (int j = 0; j < 4; ++j) {
            float f = r_lds[mi * 16 + row0 + j];
#pragma unroll
            for (int ni = 0; ni < 4; ++ni) acc[mi][ni][j] *= f;
          }
        const int arow = lane & 15, kq = (lane >> 4) * 8;
#pragma unroll
        for (int kk = 0; kk < 2; ++kk) {
          bf16x8 pa0 = *(const bf16x8*)&Ps[arow][kk * 32 + kq];
          bf16x8 pa1 = *(const bf16x8*)&Ps[16 + arow][kk * 32 + kq];
#pragma unroll
          for (int ni = 0; ni < 4; ++ni) {
            bf16x8 bv = *(const bf16x8*)&Vts[w * 64 + ni * 16 + arow][kk * 32 + kq];
            acc[0][ni] = mfma16(pa0, bv, acc[0][ni]);
            acc[1][ni] = mfma16(pa1, bv, acc[1][ni]);
          }
        }
      }
      __syncthreads();
    }
    {  // epilogue: normalize + f32 store
      const int row0 = (lane >> 4) * 4, col = lane & 15;
#pragma unroll
      for (int mi = 0; mi < 2; ++mi)
#pragma unroll
        for (int j = 0; j < 4; ++j) {
          int qr = mi * 16 + row0 + j;
          float inv = 1.0f / l_lds[qr];
#pragma unroll
          for (int ni = 0; ni < 4; ++ni) {
            Ob[(size_t)(q0 + qr) * ND + w * 64 + ni * 16 + col] = acc[mi][ni][j] * inv;
          }
        }
    }
  }
}

extern "C" void kernel_launch(void* const* d_in, const int* in_sizes, int n_in,
                              void* d_out, int out_size, void* d_ws, size_t ws_size,
                              hipStream_t stream) {
  const float* Xk = (const float*)d_in[0];
  const float* Xv = (const float*)d_in[1];
  const float* Xq = (const float*)d_in[2];
  const float* Wq = (const float*)d_in[3];
  const float* Wk = (const float*)d_in[4];
  const float* Wv = (const float*)d_in[5];
  float* Out = (float*)d_out;

  char* ws = (char*)d_ws;
  bf16* Qb = (bf16*)(ws);                                    // 16 MB
  bf16* Kb = (bf16*)(ws + (size_t)16 * 1024 * 1024);         // 16 MB
  bf16* Vt = (bf16*)(ws + (size_t)32 * 1024 * 1024);         // 16 MB (transposed)
  bf16* Wt = (bf16*)(ws + (size_t)48 * 1024 * 1024);         // 1.5 MB (3x 512x512)

  hipLaunchKernelGGL(wconv_kernel, dim3(3072), dim3(256), 0, stream, Wq, Wk, Wv, Wt);
  hipLaunchKernelGGL(proj_kernel, dim3(128, 4), dim3(256), 0, stream, Xq, Wt, Qb, 0);
  hipLaunchKernelGGL(proj_kernel, dim3(128, 4), dim3(256), 0, stream, Xk, Wt + 262144, Kb, 0);
  hipLaunchKernelGGL(proj_kernel, dim3(128, 4), dim3(256), 0, stream, Xv, Wt + 524288, Vt, 1);
  hipLaunchKernelGGL(attn_kernel, dim3(32, 8), dim3(512), 0, stream, Qb, Kb, Vt, Out);
}

// Round 3
// 202.711 us; speedup vs baseline: 1.3183x; 1.3183x over previous
//
#include <hip/hip_runtime.h>
#include <hip/hip_bf16.h>

typedef __bf16 bf16;
typedef __bf16 bf16x4 __attribute__((ext_vector_type(4)));
typedef __bf16 bf16x8 __attribute__((ext_vector_type(8)));
typedef float f32x4 __attribute__((ext_vector_type(4)));
typedef float f32x16 __attribute__((ext_vector_type(16)));

#define NB 8
#define NS 2048
#define ND 512

static __device__ __forceinline__ f32x4 mfma16(bf16x8 a, bf16x8 b, f32x4 c) {
  return __builtin_amdgcn_mfma_f32_16x16x32_bf16(a, b, c, 0, 0, 0);
}
static __device__ __forceinline__ f32x16 mfma32(bf16x8 a, bf16x8 b, f32x16 c) {
  return __builtin_amdgcn_mfma_f32_32x32x16_bf16(a, b, c, 0, 0, 0);
}
static __device__ __forceinline__ void async16(const bf16* g, bf16* l) {
  __builtin_amdgcn_global_load_lds((const __attribute__((address_space(1))) void*)g,
                                   (__attribute__((address_space(3))) void*)l, 16, 0, 0);
}

// ---- kernel 0: W[k][n] (f32) -> Wt[n][k] (bf16), 3 weights concatenated ----
__global__ void wconv_kernel(const float* __restrict__ Wq,
                             const float* __restrict__ Wk,
                             const float* __restrict__ Wv,
                             bf16* __restrict__ Wt) {
  int idx = blockIdx.x * 256 + threadIdx.x;        // 3 * 512 * 512
  int w = idx >> 18;
  int rem = idx & ((1 << 18) - 1);
  int n = rem >> 9, k = rem & 511;
  const float* W = (w == 0) ? Wq : (w == 1) ? Wk : Wv;
  Wt[idx] = (bf16)W[k * 512 + n];
}

// ---- kernel 1: C[16384,512] = A_f32[16384,512] @ W, bf16 out ----
// vmode=0: plain row-major (Q)
// vmode=1: row-major, column XOR-swizzled per row (K for attn LDS)
// vmode=2: per-batch transposed [B][512][2048], s XOR-swizzled within 64-tiles (V^T)
__launch_bounds__(256)
__global__ void proj_kernel(const float* __restrict__ A,
                            const bf16* __restrict__ Wt,   // [512 n][512 k]
                            bf16* __restrict__ C,
                            int vmode) {
  __shared__ bf16 As[2][128][72];
  __shared__ bf16 Ws[2][128][72];
  const int t = threadIdx.x;
  const int lane = t & 63;
  const int w = t >> 6;
  const int wr = w >> 1, wc = w & 1;                // 2x2 waves, 64x64 each
  const int bm = blockIdx.x * 128;
  const int bn = blockIdx.y * 128;

  f32x4 acc[4][4] = {};

  auto stageA = [&](int kc, int bufi) {
    int r0 = t >> 4, seg = t & 15;
#pragma unroll
    for (int p = 0; p < 8; ++p) {
      int r = p * 16 + r0;
      float4 v = *(const float4*)(A + (size_t)(bm + r) * 512 + kc * 64 + seg * 4);
      bf16x4 o = {(bf16)v.x, (bf16)v.y, (bf16)v.z, (bf16)v.w};
      *(bf16x4*)&As[bufi][r][seg * 4] = o;
    }
  };
  auto stageW = [&](int kc, int bufi) {
    int n0 = t >> 3, seg = t & 7;
#pragma unroll
    for (int p = 0; p < 4; ++p) {
      int n = p * 32 + n0;
      bf16x8 v = *(const bf16x8*)(Wt + (size_t)(bn + n) * 512 + kc * 64 + seg * 8);
      *(bf16x8*)&Ws[bufi][n][seg * 8] = v;
    }
  };

  stageA(0, 0);
  stageW(0, 0);
  __syncthreads();
  int buf = 0;
  for (int kc = 0; kc < 8; ++kc) {
    if (kc < 7) { stageA(kc + 1, buf ^ 1); stageW(kc + 1, buf ^ 1); }
    const int arow = lane & 15, kq = (lane >> 4) * 8;
#pragma unroll
    for (int kk = 0; kk < 2; ++kk) {
      bf16x8 af[4], bfr[4];
#pragma unroll
      for (int mi = 0; mi < 4; ++mi)
        af[mi] = *(const bf16x8*)&As[buf][wr * 64 + mi * 16 + arow][kk * 32 + kq];
#pragma unroll
      for (int ni = 0; ni < 4; ++ni)
        bfr[ni] = *(const bf16x8*)&Ws[buf][wc * 64 + ni * 16 + arow][kk * 32 + kq];
#pragma unroll
      for (int mi = 0; mi < 4; ++mi)
#pragma unroll
        for (int ni = 0; ni < 4; ++ni)
          acc[mi][ni] = mfma16(af[mi], bfr[ni], acc[mi][ni]);
    }
    __syncthreads();
    buf ^= 1;
  }

  // epilogue: C/D layout col=lane&15, row=(lane>>4)*4+j  [m89]
  const int row0 = (lane >> 4) * 4, col = lane & 15;
#pragma unroll
  for (int mi = 0; mi < 4; ++mi)
#pragma unroll
    for (int ni = 0; ni < 4; ++ni) {
      int cg = bn + wc * 64 + ni * 16 + col;
#pragma unroll
      for (int j = 0; j < 4; ++j) {
        int rg = bm + wr * 64 + mi * 16 + row0 + j;
        bf16 o = (bf16)acc[mi][ni][j];
        if (vmode == 0) {
          C[(size_t)rg * ND + cg] = o;
        } else if (vmode == 1) {
          C[(size_t)rg * ND + (cg ^ ((rg & 7) << 3))] = o;
        } else {
          int bb = rg >> 11, s = rg & 2047;
          int ss = (s & ~63) | ((s & 63) ^ ((cg & 7) << 3));
          C[(size_t)bb * (ND * NS) + (size_t)cg * NS + ss] = o;
        }
      }
    }
}

// ---- kernel 2: causal flash attention ----
// 256 blocks: batch = id&7 (XCD pinning), qt = id>>3 in [0,32) -> 64 q-rows.
// 8 waves: (sm,sn,sk) = (q-half, kv-half, k-half). Per 64-wide KV tile:
// DMA-stage K (64x512) + V^T (512x64) -> QK^T (16 mfma32/wave, LDS partial
// reduce over sk) -> wave-parallel online softmax -> PV (16 mfma32/wave,
// D split across waves). K/V^T globals are pre-XOR-swizzled so linear DMA +
// swizzled ds_read_b128 sits at the LDS bank floor.
__launch_bounds__(512, 2)
__global__ void attn_kernel(const bf16* __restrict__ Qg,    // [B][S][D] plain
                            const bf16* __restrict__ Kg,    // [B][S][D] col-swizzled
                            const bf16* __restrict__ Vtg,   // [B][D][S] s-swizzled
                            float* __restrict__ Out) {      // [B][S][D]
  __shared__ bf16 Ks[64][512];     // 64 KB
  __shared__ bf16 Vts[512][64];    // 64 KB
  __shared__ float Ss[64][64];     // 16 KB scores / partial-sum buffer
  __shared__ bf16 Ps[64][72];      // 9 KB P (bf16), padded
  __shared__ float m_lds[64], l_lds[64], r_lds[64];

  const int t = threadIdx.x;
  const int lane = t & 63;
  const int w = t >> 6;
  const int id = blockIdx.x;
  const int b = id & 7;            // batch == XCD
  const int qt = id >> 3;          // 0..31
  const int q0 = qt * 64;
  const int sm = w >> 2, sn = (w >> 1) & 1, sk = w & 1;
  const int l31 = lane & 31, lhi = lane >> 5;

  const bf16* Qb = Qg + (size_t)b * NS * ND;
  const bf16* Kb = Kg + (size_t)b * NS * ND;
  const bf16* Vb = Vtg + (size_t)b * ND * NS;
  float* Ob = Out + (size_t)b * NS * ND;

  const float SC = 0.04419417382415922f * 1.4426950408889634f;  // rsqrt(512)*log2e

  if (t < 64) { m_lds[t] = -1e30f; l_lds[t] = 0.0f; }

  // Q fragments in registers: Q[q0 + sm*32 + l31][sk*256 + c*16 + lhi*8 + e]
  bf16x8 qf[16];
  {
    const bf16* qrow = Qb + (size_t)(q0 + sm * 32 + l31) * ND + sk * 256 + lhi * 8;
#pragma unroll
    for (int c = 0; c < 16; ++c) qf[c] = *(const bf16x8*)(qrow + c * 16);
  }
  f32x16 acc[2][2] = {};

  const int n_tiles = qt + 1;
  for (int it = 0; it < n_tiles; ++it) {
    const int k0 = it * 64;
    // ---- stage K (64x512) and V^T (512x64) via global_load_lds ----
    {
      const bf16* gp = Kb + (size_t)(k0 + w * 8) * ND + lane * 8;
      bf16* lp = &Ks[w * 8][0];
#pragma unroll
      for (int i = 0; i < 8; ++i) async16(gp + (size_t)i * ND, lp + i * 512);
    }
    {
      const bf16* gp = Vb + (size_t)(w * 64 + (lane >> 3)) * NS + k0 + (lane & 7) * 8;
      bf16* lp = &Vts[w * 64][0];
#pragma unroll
      for (int i = 0; i < 8; ++i) async16(gp + (size_t)i * 8 * NS, lp + i * 8 * 64);
    }
    __syncthreads();  // B1: staged (vmcnt drained at barrier)

    // ---- QK^T: wave (sm,sn,sk): 32q x 32kv over K=256 -> 16 MFMAs ----
    f32x16 sacc = {};
    const int kvr = sn * 32 + l31;
    const int swz = (kvr & 7) << 3;
#pragma unroll
    for (int kc = 0; kc < 16; ++kc) {
      int col = (sk * 256 + kc * 16 + lhi * 8) ^ swz;
      bf16x8 bfrag = *(const bf16x8*)&Ks[kvr][col];
      sacc = mfma32(qf[kc], bfrag, sacc);
    }
    if (sk) {
#pragma unroll
      for (int j = 0; j < 16; ++j) {
        int row = (j & 3) + 8 * (j >> 2) + 4 * lhi;
        Ss[sm * 32 + row][sn * 32 + l31] = sacc[j];
      }
    }
    __syncthreads();  // B2
    if (!sk) {
#pragma unroll
      for (int j = 0; j < 16; ++j) {
        int row = (j & 3) + 8 * (j >> 2) + 4 * lhi;
        int q = sm * 32 + row, kvc = sn * 32 + l31;
        float v = (sacc[j] + Ss[q][kvc]) * SC;
        if (k0 + kvc > q0 + q) v = -1e30f;
        Ss[q][kvc] = v;
      }
    }
    __syncthreads();  // B3

    // ---- online softmax: 8 lanes per row, 64 rows ----
    {
      const int row = t >> 3, sub = t & 7;
      float4 a = *(const float4*)&Ss[row][sub * 8];
      float4 c = *(const float4*)&Ss[row][sub * 8 + 4];
      float mx = fmaxf(fmaxf(fmaxf(a.x, a.y), fmaxf(a.z, a.w)),
                       fmaxf(fmaxf(c.x, c.y), fmaxf(c.z, c.w)));
#pragma unroll
      for (int d = 1; d < 8; d <<= 1) mx = fmaxf(mx, __shfl_xor(mx, d));
      float m_old = m_lds[row];
      float m_new = fmaxf(m_old, mx);
      float p0 = exp2f(a.x - m_new), p1 = exp2f(a.y - m_new);
      float p2 = exp2f(a.z - m_new), p3 = exp2f(a.w - m_new);
      float p4 = exp2f(c.x - m_new), p5 = exp2f(c.y - m_new);
      float p6 = exp2f(c.z - m_new), p7 = exp2f(c.w - m_new);
      float sum = ((p0 + p1) + (p2 + p3)) + ((p4 + p5) + (p6 + p7));
#pragma unroll
      for (int d = 1; d < 8; d <<= 1) sum += __shfl_xor(sum, d);
      bf16x8 pv = {(bf16)p0, (bf16)p1, (bf16)p2, (bf16)p3,
                   (bf16)p4, (bf16)p5, (bf16)p6, (bf16)p7};
      *(bf16x8*)&Ps[row][sub * 8] = pv;
      if (sub == 0) {
        float rs = exp2f(m_old - m_new);
        r_lds[row] = rs;
        m_lds[row] = m_new;
        l_lds[row] = l_lds[row] * rs + sum;
      }
    }
    __syncthreads();  // B4

    // ---- PV: wave w owns d cols [w*64, w*64+64); 16 MFMAs ----
#pragma unroll
    for (int mi = 0; mi < 2; ++mi)
#pragma unroll
      for (int j = 0; j < 16; ++j) {
        int row = mi * 32 + (j & 3) + 8 * (j >> 2) + 4 * lhi;
        float rs = r_lds[row];
        acc[mi][0][j] *= rs;
        acc[mi][1][j] *= rs;
      }
#pragma unroll
    for (int kc = 0; kc < 4; ++kc) {
      const int kv0 = kc * 16 + lhi * 8;
      bf16x8 pa[2], vb[2];
#pragma unroll
      for (int mi = 0; mi < 2; ++mi)
        pa[mi] = *(const bf16x8*)&Ps[mi * 32 + l31][kv0];
#pragma unroll
      for (int ni = 0; ni < 2; ++ni) {
        int d = w * 64 + ni * 32 + l31;
        vb[ni] = *(const bf16x8*)&Vts[d][kv0 ^ ((d & 7) << 3)];
      }
#pragma unroll
      for (int mi = 0; mi < 2; ++mi)
#pragma unroll
        for (int ni = 0; ni < 2; ++ni)
          acc[mi][ni] = mfma32(pa[mi], vb[ni], acc[mi][ni]);
    }
    __syncthreads();  // B5: PV done reading Ks/Vts/Ps before restage
  }

  // ---- epilogue: normalize + f32 store ----
#pragma unroll
  for (int mi = 0; mi < 2; ++mi)
#pragma unroll
    for (int j = 0; j < 16; ++j) {
      int row = mi * 32 + (j & 3) + 8 * (j >> 2) + 4 * lhi;
      float inv = 1.0f / l_lds[row];
#pragma unroll
      for (int ni = 0; ni < 2; ++ni)
        Ob[(size_t)(q0 + row) * ND + w * 64 + ni * 32 + l31] = acc[mi][ni][j] * inv;
    }
}

extern "C" void kernel_launch(void* const* d_in, const int* in_sizes, int n_in,
                              void* d_out, int out_size, void* d_ws, size_t ws_size,
                              hipStream_t stream) {
  const float* Xk = (const float*)d_in[0];
  const float* Xv = (const float*)d_in[1];
  const float* Xq = (const float*)d_in[2];
  const float* Wq = (const float*)d_in[3];
  const float* Wk = (const float*)d_in[4];
  const float* Wv = (const float*)d_in[5];
  float* Out = (float*)d_out;

  char* ws = (char*)d_ws;
  bf16* Qb = (bf16*)(ws);                                    // 16 MB
  bf16* Kb = (bf16*)(ws + (size_t)16 * 1024 * 1024);         // 16 MB (swizzled)
  bf16* Vt = (bf16*)(ws + (size_t)32 * 1024 * 1024);         // 16 MB (transposed+swizzled)
  bf16* Wt = (bf16*)(ws + (size_t)48 * 1024 * 1024);         // 1.5 MB (3x 512x512)

  hipLaunchKernelGGL(wconv_kernel, dim3(3072), dim3(256), 0, stream, Wq, Wk, Wv, Wt);
  hipLaunchKernelGGL(proj_kernel, dim3(128, 4), dim3(256), 0, stream, Xq, Wt, Qb, 0);
  hipLaunchKernelGGL(proj_kernel, dim3(128, 4), dim3(256), 0, stream, Xk, Wt + 262144, Kb, 1);
  hipLaunchKernelGGL(proj_kernel, dim3(128, 4), dim3(256), 0, stream, Xv, Wt + 524288, Vt, 2);
  hipLaunchKernelGGL(attn_kernel, dim3(256), dim3(512), 0, stream, Qb, Kb, Vt, Out);
}

// Round 5
// 162.664 us; speedup vs baseline: 1.6429x; 1.2462x over previous
//
#include <hip/hip_runtime.h>
#include <hip/hip_bf16.h>

typedef __bf16 bf16;
typedef __bf16 bf16x4 __attribute__((ext_vector_type(4)));
typedef __bf16 bf16x8 __attribute__((ext_vector_type(8)));
typedef float f32x4 __attribute__((ext_vector_type(4)));
typedef float f32x16 __attribute__((ext_vector_type(16)));

#define NB 8
#define NS 2048
#define ND 512

static __device__ __forceinline__ f32x4 mfma16(bf16x8 a, bf16x8 b, f32x4 c) {
  return __builtin_amdgcn_mfma_f32_16x16x32_bf16(a, b, c, 0, 0, 0);
}
static __device__ __forceinline__ f32x16 mfma32(bf16x8 a, bf16x8 b, f32x16 c) {
  return __builtin_amdgcn_mfma_f32_32x32x16_bf16(a, b, c, 0, 0, 0);
}
static __device__ __forceinline__ void async16(const bf16* g, bf16* l) {
  __builtin_amdgcn_global_load_lds((const __attribute__((address_space(1))) void*)g,
                                   (__attribute__((address_space(3))) void*)l, 16, 0, 0);
}

// raw barriers: counted vmcnt keeps prefetch DMA in flight across barriers (T3/T4)
#define BAR_VM8_LG0() do { asm volatile("s_waitcnt vmcnt(8) lgkmcnt(0)" ::: "memory"); \
  __builtin_amdgcn_s_barrier(); __builtin_amdgcn_sched_barrier(0); } while (0)
#define BAR_LG0() do { asm volatile("s_waitcnt lgkmcnt(0)" ::: "memory"); \
  __builtin_amdgcn_s_barrier(); __builtin_amdgcn_sched_barrier(0); } while (0)

// ---- kernel 0: W[k][n] (f32) -> Wt[z][n][k] (bf16), coalesced via LDS transpose.
// Wq additionally scaled by rsqrt(512)*log2e (folds softmax scale into Q).
__global__ void wconv_kernel(const float* __restrict__ Wq,
                             const float* __restrict__ Wk,
                             const float* __restrict__ Wv,
                             bf16* __restrict__ Wt) {
  __shared__ float buf[64][65];
  const int z = blockIdx.z;
  const float* W = (z == 0) ? Wq : (z == 1) ? Wk : Wv;
  const float scale = (z == 0) ? 0.063763537f : 1.0f;
  const int k0 = blockIdx.x * 64, n0 = blockIdx.y * 64;
  const int t = threadIdx.x;
#pragma unroll
  for (int i = 0; i < 16; ++i) {
    int idx = i * 256 + t;
    int kk = idx >> 6, nn = idx & 63;
    buf[kk][nn] = W[(size_t)(k0 + kk) * 512 + n0 + nn];
  }
  __syncthreads();
#pragma unroll
  for (int i = 0; i < 16; ++i) {
    int idx = i * 256 + t;
    int nn = idx >> 6, kk = idx & 63;
    Wt[(size_t)z * 262144 + (size_t)(n0 + nn) * 512 + k0 + kk] = (bf16)(buf[kk][nn] * scale);
  }
}

// ---- kernel 1: fused 3x projection C[16384,512] = A_f32 @ W, bf16 out ----
// z=0: Q plain row-major; z=1: K row-major, col XOR-swizzled per row;
// z=2: V^T per-batch [B][512][2048], s XOR-swizzled within 64-tiles.
// M-tiles remapped so batch == blockIdx.x&7 (XCD L2 pinning matches attn).
__launch_bounds__(256)
__global__ void proj_kernel(const float* __restrict__ Xq,
                            const float* __restrict__ Xk,
                            const float* __restrict__ Xv,
                            const bf16* __restrict__ Wt,
                            bf16* __restrict__ Cq,
                            bf16* __restrict__ Ck,
                            bf16* __restrict__ Cv) {
  __shared__ bf16 As[2][128][72];
  __shared__ bf16 Ws[2][128][72];
  const int z = blockIdx.z;
  const float* A = (z == 0) ? Xq : (z == 1) ? Xk : Xv;
  const bf16* Wz = Wt + (size_t)z * 262144;
  bf16* C = (z == 0) ? Cq : (z == 1) ? Ck : Cv;

  const int t = threadIdx.x;
  const int lane = t & 63;
  const int w = t >> 6;
  const int wr = w >> 1, wc = w & 1;
  const int bxr = blockIdx.x;
  const int mt = (bxr & 7) * 16 + (bxr >> 3);   // batch-pinned M-tile
  const int bm = mt * 128;
  const int bn = blockIdx.y * 128;

  f32x4 acc[4][4] = {};

  auto stageA = [&](int kc, int bufi) {
    int r0 = t >> 4, seg = t & 15;
#pragma unroll
    for (int p = 0; p < 8; ++p) {
      int r = p * 16 + r0;
      float4 v = *(const float4*)(A + (size_t)(bm + r) * 512 + kc * 64 + seg * 4);
      bf16x4 o = {(bf16)v.x, (bf16)v.y, (bf16)v.z, (bf16)v.w};
      *(bf16x4*)&As[bufi][r][seg * 4] = o;
    }
  };
  auto stageW = [&](int kc, int bufi) {
    int n0 = t >> 3, seg = t & 7;
#pragma unroll
    for (int p = 0; p < 4; ++p) {
      int n = p * 32 + n0;
      bf16x8 v = *(const bf16x8*)(Wz + (size_t)(bn + n) * 512 + kc * 64 + seg * 8);
      *(bf16x8*)&Ws[bufi][n][seg * 8] = v;
    }
  };

  stageA(0, 0);
  stageW(0, 0);
  __syncthreads();
  int buf = 0;
  for (int kc = 0; kc < 8; ++kc) {
    if (kc < 7) { stageA(kc + 1, buf ^ 1); stageW(kc + 1, buf ^ 1); }
    const int arow = lane & 15, kq = (lane >> 4) * 8;
#pragma unroll
    for (int kk = 0; kk < 2; ++kk) {
      bf16x8 af[4], bfr[4];
#pragma unroll
      for (int mi = 0; mi < 4; ++mi)
        af[mi] = *(const bf16x8*)&As[buf][wr * 64 + mi * 16 + arow][kk * 32 + kq];
#pragma unroll
      for (int ni = 0; ni < 4; ++ni)
        bfr[ni] = *(const bf16x8*)&Ws[buf][wc * 64 + ni * 16 + arow][kk * 32 + kq];
#pragma unroll
      for (int mi = 0; mi < 4; ++mi)
#pragma unroll
        for (int ni = 0; ni < 4; ++ni)
          acc[mi][ni] = mfma16(af[mi], bfr[ni], acc[mi][ni]);
    }
    __syncthreads();
    buf ^= 1;
  }

  const int row0 = (lane >> 4) * 4, col = lane & 15;
#pragma unroll
  for (int mi = 0; mi < 4; ++mi)
#pragma unroll
    for (int ni = 0; ni < 4; ++ni) {
      int cg = bn + wc * 64 + ni * 16 + col;
#pragma unroll
      for (int j = 0; j < 4; ++j) {
        int rg = bm + wr * 64 + mi * 16 + row0 + j;
        bf16 o = (bf16)acc[mi][ni][j];
        if (z == 0) {
          C[(size_t)rg * ND + cg] = o;
        } else if (z == 1) {
          C[(size_t)rg * ND + (cg ^ ((rg & 7) << 3))] = o;
        } else {
          int bb = rg >> 11, s = rg & 2047;
          int ss = (s & ~63) | ((s & 63) ^ ((cg & 7) << 3));
          C[(size_t)bb * (ND * NS) + (size_t)cg * NS + ss] = o;
        }
      }
    }
}

// ---- kernel 2: causal flash attention, split-KV capable ----
// NSPLIT=1: 256 blocks (b=id&7 XCD pin, qt descending), direct f32 out.
// NSPLIT=2: 512 blocks, h=id>>8 picks KV-half; bf16 normalized partials + m,l.
// Pipeline per 64-KV tile (counted vmcnt, never 0 in loop):
//  B1[vm8] QK(mfma16, full K=512/wave) B2[lg0] stageK(next) softmax
//  B3[vm8+lg0] PV(mfma32) B4[lg0] stageV(next)
template<int NSPLIT>
__launch_bounds__(512, 2)
__global__ void attn_kernel(const bf16* __restrict__ Qg,
                            const bf16* __restrict__ Kg,
                            const bf16* __restrict__ Vtg,
                            float* __restrict__ Out,
                            bf16* __restrict__ Pn,
                            float* __restrict__ Mp,
                            float* __restrict__ Lp) {
  __shared__ bf16 Ks[64][512];
  __shared__ bf16 Vts[512][64];
  __shared__ float Ss[64][68];
  __shared__ bf16 Ps[64][72];
  __shared__ float m_lds[64], l_lds[64], r_lds[64];

  const int t = threadIdx.x;
  const int lane = t & 63;
  const int w = t >> 6;
  const int id = blockIdx.x;
  const int b = id & 7;
  const int qt = 31 - ((id >> 3) & 31);      // descending size for greedy backfill
  const int h = (NSPLIT == 2) ? (id >> 8) : 0;
  const int q0 = qt * 64;
  const int sm = w >> 1, sn = w & 1;          // mfma16 QK: q-quarter x kv-half
  const int l15 = lane & 15, lq = lane >> 4;
  const int l31 = lane & 31, lhi = lane >> 5;

  int t_begin, t_end;
  {
    int nt = qt + 1;
    int mid = (nt + 1) >> 1;
    if (NSPLIT == 2) { t_begin = h ? mid : 0; t_end = h ? nt : mid; }
    else { t_begin = 0; t_end = nt; }
  }
  const int pidx = (h * 8 + b) * 32 + qt;

  if (NSPLIT == 2 && t_begin >= t_end) {       // empty half (qt=0,h=1)
    if (t < 64) { Mp[pidx * 64 + t] = -1e30f; Lp[pidx * 64 + t] = 0.0f; }
    return;
  }

  const bf16* Qb = Qg + (size_t)b * NS * ND;
  const bf16* Kb = Kg + (size_t)b * NS * ND;
  const bf16* Vb = Vtg + (size_t)b * ND * NS;

  if (t < 64) { m_lds[t] = -1e30f; l_lds[t] = 0.0f; }

  // Q fragments (A of mfma16): row = q0+sm*16+l15, k = kc*32 + lq*8 + e
  bf16x8 qf[16];
  {
    const bf16* qrow = Qb + (size_t)(q0 + sm * 16 + l15) * ND + lq * 8;
#pragma unroll
    for (int kc = 0; kc < 16; ++kc) qf[kc] = *(const bf16x8*)(qrow + kc * 32);
  }
  f32x16 acc[2][2] = {};

  auto stageK = [&](int k0s) {
#pragma unroll
    for (int i = 0; i < 8; ++i)
      async16(Kb + (size_t)(k0s + w * 8 + i) * ND + lane * 8, &Ks[w * 8 + i][0]);
  };
  auto stageV = [&](int k0s) {
#pragma unroll
    for (int i = 0; i < 8; ++i)
      async16(Vb + (size_t)(w * 64 + i * 8 + (lane >> 3)) * NS + k0s + (lane & 7) * 8,
              &Vts[w * 64 + i * 8][0]);
  };

  stageK(t_begin * 64);   // 8 loads/thread (older)
  stageV(t_begin * 64);   // 8 loads/thread (newer)

  for (int it = t_begin; it < t_end; ++it) {
    const int k0 = it * 64;
    const int nx = (it + 1 < t_end ? it + 1 : it) * 64;   // clamp keeps count=8
    BAR_VM8_LG0();   // B1: K(it) landed; V(it) may still fly

    // ---- QK^T: per wave 16q x 32kv, full K=512, 32 mfma16 ----
    f32x4 s0 = {}, s1 = {};
    const int kr0 = sn * 32 + l15, kr1 = kr0 + 16;
    const int swz = (l15 & 7) << 3;
#pragma unroll
    for (int kc = 0; kc < 16; ++kc) {
      const int colb = (kc * 32 + lq * 8) ^ swz;
      bf16x8 b0 = *(const bf16x8*)&Ks[kr0][colb];
      bf16x8 b1 = *(const bf16x8*)&Ks[kr1][colb];
      s0 = mfma16(qf[kc], b0, s0);
      s1 = mfma16(qf[kc], b1, s1);
    }
    {  // write scores (pre-scaled via Wq fold); mask only the diagonal tile
      const bool mask = (it == qt);
#pragma unroll
      for (int j = 0; j < 4; ++j) {
        const int qr = sm * 16 + lq * 4 + j;
        float v0 = s0[j], v1 = s1[j];
        if (mask) {
          if (k0 + kr0 > q0 + qr) v0 = -1e30f;
          if (k0 + kr1 > q0 + qr) v1 = -1e30f;
        }
        Ss[qr][kr0] = v0;
        Ss[qr][kr1] = v1;
      }
    }
    BAR_LG0();       // B2: scores visible; all QK reads of Ks retired
    stageK(nx);      // prefetch next K (window: softmax+PV)

    // ---- online softmax: 8 lanes per row ----
    {
      const int row = t >> 3, sub = t & 7;
      float4 a = *(const float4*)&Ss[row][sub * 8];
      float4 c = *(const float4*)&Ss[row][sub * 8 + 4];
      float mx = fmaxf(fmaxf(fmaxf(a.x, a.y), fmaxf(a.z, a.w)),
                       fmaxf(fmaxf(c.x, c.y), fmaxf(c.z, c.w)));
#pragma unroll
      for (int d = 1; d < 8; d <<= 1) mx = fmaxf(mx, __shfl_xor(mx, d));
      float m_old = m_lds[row];
      float m_new = fmaxf(m_old, mx);
      float p0 = exp2f(a.x - m_new), p1 = exp2f(a.y - m_new);
      float p2 = exp2f(a.z - m_new), p3 = exp2f(a.w - m_new);
      float p4 = exp2f(c.x - m_new), p5 = exp2f(c.y - m_new);
      float p6 = exp2f(c.z - m_new), p7 = exp2f(c.w - m_new);
      float sum = ((p0 + p1) + (p2 + p3)) + ((p4 + p5) + (p6 + p7));
#pragma unroll
      for (int d = 1; d < 8; d <<= 1) sum += __shfl_xor(sum, d);
      bf16x8 pv = {(bf16)p0, (bf16)p1, (bf16)p2, (bf16)p3,
                   (bf16)p4, (bf16)p5, (bf16)p6, (bf16)p7};
      *(bf16x8*)&Ps[row][sub * 8] = pv;
      if (sub == 0) {
        float rs = exp2f(m_old - m_new);
        r_lds[row] = rs;
        m_lds[row] = m_new;
        l_lds[row] = l_lds[row] * rs + sum;
      }
    }
    BAR_VM8_LG0();   // B3: V(it) landed; K(it+1) still flying; Ps visible

    // ---- PV: wave w owns d in [w*64, w*64+64) ----
#pragma unroll
    for (int mi = 0; mi < 2; ++mi)
#pragma unroll
      for (int j = 0; j < 16; ++j) {
        int row = mi * 32 + (j & 3) + 8 * (j >> 2) + 4 * lhi;
        float rs = r_lds[row];
        acc[mi][0][j] *= rs;
        acc[mi][1][j] *= rs;
      }
#pragma unroll
    for (int kc = 0; kc < 4; ++kc) {
      const int kv0 = kc * 16 + lhi * 8;
      bf16x8 pa0 = *(const bf16x8*)&Ps[l31][kv0];
      bf16x8 pa1 = *(const bf16x8*)&Ps[32 + l31][kv0];
      bf16x8 vb0, vb1;
      { int d0 = w * 64 + l31;      vb0 = *(const bf16x8*)&Vts[d0][kv0 ^ ((d0 & 7) << 3)]; }
      { int d1 = w * 64 + 32 + l31; vb1 = *(const bf16x8*)&Vts[d1][kv0 ^ ((d1 & 7) << 3)]; }
      acc[0][0] = mfma32(pa0, vb0, acc[0][0]);
      acc[0][1] = mfma32(pa0, vb1, acc[0][1]);
      acc[1][0] = mfma32(pa1, vb0, acc[1][0]);
      acc[1][1] = mfma32(pa1, vb1, acc[1][1]);
    }
    BAR_LG0();       // B4: PV reads of Vts/Ps retired
    stageV(nx);      // prefetch next V (window: QK+softmax of next tile)
  }

  // ---- epilogue ----
  if (NSPLIT == 2) {
    if (t < 64) { Mp[pidx * 64 + t] = m_lds[t]; Lp[pidx * 64 + t] = l_lds[t]; }
    bf16* Ob = Pn + (size_t)pidx * 64 * ND;
#pragma unroll
    for (int mi = 0; mi < 2; ++mi)
#pragma unroll
      for (int j = 0; j < 16; ++j) {
        int row = mi * 32 + (j & 3) + 8 * (j >> 2) + 4 * lhi;
        float inv = 1.0f / l_lds[row];
#pragma unroll
        for (int ni = 0; ni < 2; ++ni)
          Ob[(size_t)row * ND + w * 64 + ni * 32 + l31] = (bf16)(acc[mi][ni][j] * inv);
      }
  } else {
    float* Ob = Out + (size_t)b * NS * ND;
#pragma unroll
    for (int mi = 0; mi < 2; ++mi)
#pragma unroll
      for (int j = 0; j < 16; ++j) {
        int row = mi * 32 + (j & 3) + 8 * (j >> 2) + 4 * lhi;
        float inv = 1.0f / l_lds[row];
#pragma unroll
        for (int ni = 0; ni < 2; ++ni)
          __builtin_nontemporal_store(acc[mi][ni][j] * inv,
              &Ob[(size_t)(q0 + row) * ND + w * 64 + ni * 32 + l31]);
      }
  }
}

// ---- kernel 3: combine two KV-half partials ----
__global__ void combine_kernel(const bf16* __restrict__ Pn,
                               const float* __restrict__ Mp,
                               const float* __restrict__ Lp,
                               float* __restrict__ Out) {
  const int total = NB * NS * ND / 4;
  for (int v = blockIdx.x * 256 + threadIdx.x; v < total; v += gridDim.x * 256) {
    int e = v * 4;
    int d = e & 511;
    int s = (e >> 9) & 2047;
    int bb = e >> 20;
    int qt = s >> 6, r = s & 63;
    int p0 = (bb * 32 + qt) * 64 + r;
    int p1 = ((8 + bb) * 32 + qt) * 64 + r;
    float m0 = Mp[p0], l0 = Lp[p0], m1 = Mp[p1], l1 = Lp[p1];
    float M = fmaxf(m0, m1);
    float w0 = l0 * exp2f(m0 - M), w1 = l1 * exp2f(m1 - M);
    float inv = 1.0f / (w0 + w1);
    bf16x4 o0 = *(const bf16x4*)(Pn + (size_t)p0 * ND + d);
    bf16x4 o1 = *(const bf16x4*)(Pn + (size_t)p1 * ND + d);
    f32x4 o;
    o[0] = (w0 * (float)o0[0] + w1 * (float)o1[0]) * inv;
    o[1] = (w0 * (float)o0[1] + w1 * (float)o1[1]) * inv;
    o[2] = (w0 * (float)o0[2] + w1 * (float)o1[2]) * inv;
    o[3] = (w0 * (float)o0[3] + w1 * (float)o1[3]) * inv;
    __builtin_nontemporal_store(o, (f32x4*)(Out + e));
  }
}

extern "C" void kernel_launch(void* const* d_in, const int* in_sizes, int n_in,
                              void* d_out, int out_size, void* d_ws, size_t ws_size,
                              hipStream_t stream) {
  const float* Xk = (const float*)d_in[0];
  const float* Xv = (const float*)d_in[1];
  const float* Xq = (const float*)d_in[2];
  const float* Wq = (const float*)d_in[3];
  const float* Wk = (const float*)d_in[4];
  const float* Wv = (const float*)d_in[5];
  float* Out = (float*)d_out;

  char* ws = (char*)d_ws;
  bf16* Qb = (bf16*)(ws);                                    // 16 MB
  bf16* Kb = (bf16*)(ws + (size_t)16 * 1024 * 1024);         // 16 MB (swizzled)
  bf16* Vt = (bf16*)(ws + (size_t)32 * 1024 * 1024);         // 16 MB (transposed+swizzled)
  bf16* Wt = (bf16*)(ws + (size_t)48 * 1024 * 1024);         // 1.5 MB
  bf16* Pn = (bf16*)(ws + (size_t)50 * 1024 * 1024);         // 32 MB partials
  float* Mp = (float*)(ws + (size_t)82 * 1024 * 1024);       // 128 KB
  float* Lp = (float*)(ws + (size_t)82 * 1024 * 1024 + 131072);
  const bool split = ws_size >= (size_t)83 * 1024 * 1024;

  wconv_kernel<<<dim3(8, 8, 3), 256, 0, stream>>>(Wq, Wk, Wv, Wt);
  proj_kernel<<<dim3(128, 4, 3), 256, 0, stream>>>(Xq, Xk, Xv, Wt, Qb, Kb, Vt);
  if (split) {
    attn_kernel<2><<<512, 512, 0, stream>>>(Qb, Kb, Vt, Out, Pn, Mp, Lp);
    combine_kernel<<<2048, 256, 0, stream>>>(Pn, Mp, Lp, Out);
  } else {
    attn_kernel<1><<<256, 512, 0, stream>>>(Qb, Kb, Vt, Out, Pn, Mp, Lp);
  }
}